// Round 4
// baseline (443.321 us; speedup 1.0000x reference)
//
#include <hip/hip_runtime.h>
#include <hip/hip_bf16.h>
#include <stdint.h>

#define B_ 64
#define N_ 4096
#define D_ 128
#define S_ 7
#define EPS_ 1e-8f
#define LN_EPS_ 1e-5f

typedef float  f32x4  __attribute__((ext_vector_type(4)));
typedef __bf16 bf16x8 __attribute__((ext_vector_type(8)));

__device__ __forceinline__ uint16_t f2bfbits(float f) {
    uint32_t x = __float_as_uint(f);
    return (uint16_t)((x + 0x7fffu + ((x >> 16) & 1u)) >> 16);  // RNE
}
__device__ __forceinline__ uint32_t pk2(float a, float b) {
    return (uint32_t)f2bfbits(a) | ((uint32_t)f2bfbits(b) << 16);
}
__device__ __forceinline__ bf16x8 ldfrag_w(const float* wp) {
    f32x4 w0 = *(const f32x4*)wp, w1 = *(const f32x4*)(wp + 4);
    bf16x8 r;
    #pragma unroll
    for (int c = 0; c < 4; ++c) { r[c] = (__bf16)w0[c]; r[4 + c] = (__bf16)w1[c]; }
    return r;
}

// ---------------------------------------------------------------------------
// K0 (448 blocks x 256): block<448 computes slots row (mu+scale*noise), LN,
//     q-proj (initial q). Strided: Wsw swizzle + qbf pad-row zeroing.
// ---------------------------------------------------------------------------
__global__ __launch_bounds__(256) void k_prep(
    const float* __restrict__ noise, const float* __restrict__ Wk,
    const float* __restrict__ Wv, const float* __restrict__ mu,
    const float* __restrict__ logsigma, const float* __restrict__ Wq,
    const float* __restrict__ lsg, const float* __restrict__ lsb,
    uint16_t* __restrict__ Wsw, float* __restrict__ slots,
    uint16_t* __restrict__ qbf) {
    const int t = threadIdx.x;
    const int tid = blockIdx.x * 256 + t;
    __shared__ float sn[128];
    __shared__ float red[2];
    {
        int row = blockIdx.x;  // always < 448
        int b = row / 7, s = row - b * 7;
        bool act = t < 128;
        float v = 0.f;
        if (act) {
            float sc = log1pf(__expf(logsigma[t])) + 1e-5f;
            v = mu[t] + sc * noise[row * 128 + t];
            slots[row * 128 + t] = v;
        }
        float sv = act ? v : 0.f;
        #pragma unroll
        for (int m = 1; m < 64; m <<= 1) sv += __shfl_xor(sv, m);
        if (act && (t & 63) == 0) red[t >> 6] = sv;
        __syncthreads();
        float mean = (red[0] + red[1]) * (1.0f / 128.0f);
        __syncthreads();
        float dv = act ? (v - mean) : 0.f;
        float sq = dv * dv;
        #pragma unroll
        for (int m = 1; m < 64; m <<= 1) sq += __shfl_xor(sq, m);
        if (act && (t & 63) == 0) red[t >> 6] = sq;
        __syncthreads();
        float var = (red[0] + red[1]) * (1.0f / 128.0f);
        if (act) sn[t] = dv * rsqrtf(var + LN_EPS_) * lsg[t] + lsb[t];
        __syncthreads();
        if (act) {
            const float4* wr = (const float4*)(Wq + t * 128);
            float acc = 0.f;
            #pragma unroll 8
            for (int j = 0; j < 32; ++j) {
                float4 w = wr[j];
                float4 s4 = *(const float4*)(sn + 4 * j);
                acc += w.x * s4.x + w.y * s4.y + w.z * s4.z + w.w * s4.w;
            }
            qbf[(b * 16 + s) * 128 + t] = f2bfbits(acc * 0.08838834764831843f);
        }
    }
    if (tid < 32768) {
        int j = tid & 7, ch = tid >> 3;
        int lane = ch & 63, k0 = (ch >> 6) & 3, wt = (ch >> 8) & 7, h = ch >> 11;
        int row = wt * 16 + (lane & 15);
        int col = k0 * 32 + (lane >> 4) * 8 + j;
        float w = h ? Wv[row * 128 + col] : Wk[row * 128 + col];
        Wsw[tid] = f2bfbits(w);
    }
    if (tid < 73728) {  // zero q pad rows s=7..15
        int bb = tid / 1152, rem = tid - bb * 1152;
        int s = 7 + (rem >> 7), d = rem & 127;
        qbf[(bb * 16 + s) * 128 + d] = 0;
    }
}

// ---------------------------------------------------------------------------
// K1: LN(x) in registers -> bf16 frags; K-half C=Wk*xn^T -> kbf[n][d];
//     V-half C=xn*Wv^T -> vbf_t[b][d][n]. C-tiles bounce through padded LDS
//     so all global stores are coalesced dwordx4 (16 B/lane).
// ---------------------------------------------------------------------------
__global__ __launch_bounds__(512) void k_proj(
    const float* __restrict__ x, const uint16_t* __restrict__ Wsw,
    const float* __restrict__ lng, const float* __restrict__ lnb,
    uint16_t* __restrict__ kbf, uint16_t* __restrict__ vbf_t) {
    __shared__ __align__(16) uint16_t wlds[16384];     // 32 KB weights (frag-linear)
    __shared__ __align__(16) uint16_t cb[128 * 132];   // 33 KB C-tile bounce (+4 pad)
    const int t = threadIdx.x, wv = t >> 6, lane = t & 63;
    const int lm = lane & 15, qd = lane >> 4;
    const long row0 = (long)blockIdx.x * 128;
    const int b = (int)(row0 >> 12);
    const int nloc = (int)(row0 & 4095);

    // prefetch BOTH weight halves to regs
    uint4 w0[4], w1[4];
    #pragma unroll
    for (int i = 0; i < 4; ++i) {
        w0[i] = *(const uint4*)(Wsw + (i * 512 + t) * 8);
        w1[i] = *(const uint4*)(Wsw + 16384 + (i * 512 + t) * 8);
    }

    const long xrow = row0 + wv * 16 + lm;
    const float* xp = x + xrow * 128 + qd * 8;
    f32x4 xa[8];
    #pragma unroll
    for (int k0 = 0; k0 < 4; ++k0) {
        xa[2 * k0]     = *(const f32x4*)(xp + k0 * 32);
        xa[2 * k0 + 1] = *(const f32x4*)(xp + k0 * 32 + 4);
    }
    #pragma unroll
    for (int i = 0; i < 4; ++i)
        *(uint4*)(wlds + (i * 512 + t) * 8) = w0[i];

    float s = 0.f, sq = 0.f;
    #pragma unroll
    for (int i = 0; i < 8; ++i)
        #pragma unroll
        for (int c = 0; c < 4; ++c) { float v = xa[i][c]; s += v; sq += v * v; }
    s  += __shfl_xor(s, 16);  s  += __shfl_xor(s, 32);
    sq += __shfl_xor(sq, 16); sq += __shfl_xor(sq, 32);
    float mean = s * (1.0f / 128.0f);
    float var  = sq * (1.0f / 128.0f) - mean * mean;
    float rs   = rsqrtf(var + LN_EPS_);

    bf16x8 xf[4];
    #pragma unroll
    for (int k0 = 0; k0 < 4; ++k0) {
        const float* gp = lng + k0 * 32 + qd * 8;
        const float* bp = lnb + k0 * 32 + qd * 8;
        f32x4 g0 = *(const f32x4*)(gp), g1 = *(const f32x4*)(gp + 4);
        f32x4 b0 = *(const f32x4*)(bp), b1 = *(const f32x4*)(bp + 4);
        #pragma unroll
        for (int c = 0; c < 4; ++c) {
            xf[k0][c]     = (__bf16)((xa[2 * k0][c]     - mean) * rs * g0[c] + b0[c]);
            xf[k0][4 + c] = (__bf16)((xa[2 * k0 + 1][c] - mean) * rs * g1[c] + b1[c]);
        }
    }
    __syncthreads();  // S1: wlds half0 ready

    // K-half: C[xrow=lm][d] tiles -> cb[xrow_local][d]
    #pragma unroll
    for (int mt = 0; mt < 8; ++mt) {
        f32x4 acc = {0.f, 0.f, 0.f, 0.f};
        #pragma unroll
        for (int k0 = 0; k0 < 4; ++k0) {
            bf16x8 wf = *(const bf16x8*)(wlds + ((mt * 4 + k0) * 64 + lane) * 8);
            acc = __builtin_amdgcn_mfma_f32_16x16x32_bf16(wf, xf[k0], acc, 0, 0, 0);
        }
        uint2 st; st.x = pk2(acc[0], acc[1]); st.y = pk2(acc[2], acc[3]);
        *(uint2*)(cb + (wv * 16 + lm) * 132 + mt * 16 + qd * 4) = st;
    }
    __syncthreads();  // S2: cb complete, wlds half0 reads done

    {   // coalesced copy-out: thread t -> row t>>2, 64B chunk (t&3)
        int r = t >> 2, c0 = (t & 3) * 32;
        const uint16_t* src = cb + r * 132 + c0;
        uint16_t* dst = kbf + (row0 + r) * 128 + c0;
        uint4 d0 = *(const uint4*)(src);
        uint4 d1 = *(const uint4*)(src + 8);
        uint4 d2 = *(const uint4*)(src + 16);
        uint4 d3 = *(const uint4*)(src + 24);
        *(uint4*)(dst)      = d0;
        *(uint4*)(dst + 8)  = d1;
        *(uint4*)(dst + 16) = d2;
        *(uint4*)(dst + 24) = d3;
    }
    #pragma unroll
    for (int i = 0; i < 4; ++i)
        *(uint4*)(wlds + (i * 512 + t) * 8) = w1[i];
    __syncthreads();  // S3: wlds half1 ready, cb reads done

    // V-half: C[n][d=lm] tiles -> cb[d][n_local]
    #pragma unroll
    for (int nt = 0; nt < 8; ++nt) {
        f32x4 acc = {0.f, 0.f, 0.f, 0.f};
        #pragma unroll
        for (int k0 = 0; k0 < 4; ++k0) {
            bf16x8 wf = *(const bf16x8*)(wlds + ((nt * 4 + k0) * 64 + lane) * 8);
            acc = __builtin_amdgcn_mfma_f32_16x16x32_bf16(xf[k0], wf, acc, 0, 0, 0);
        }
        uint2 st; st.x = pk2(acc[0], acc[1]); st.y = pk2(acc[2], acc[3]);
        *(uint2*)(cb + (nt * 16 + lm) * 132 + wv * 16 + qd * 4) = st;
    }
    __syncthreads();  // S4: cb complete

    {   // coalesced copy-out to vbf_t: thread t -> d row t>>2, chunk (t&3)
        int d = t >> 2, c0 = (t & 3) * 32;
        const uint16_t* src = cb + d * 132 + c0;
        uint16_t* dst = vbf_t + ((long)(b * 128 + d)) * 4096 + nloc + c0;
        uint4 d0 = *(const uint4*)(src);
        uint4 d1 = *(const uint4*)(src + 8);
        uint4 d2 = *(const uint4*)(src + 16);
        uint4 d3 = *(const uint4*)(src + 24);
        *(uint4*)(dst)      = d0;
        *(uint4*)(dst + 8)  = d1;
        *(uint4*)(dst + 16) = d2;
        *(uint4*)(dst + 24) = d3;
    }
}

// ---------------------------------------------------------------------------
// K3: scores (MFMA) -> softmax over S=7 -> bf16 attn frags in LDS ->
//     updates = v^T*attn (MFMA) -> per-block partials (NO atomics).
// ---------------------------------------------------------------------------
__global__ __launch_bounds__(512) void k_attn(
    const uint16_t* __restrict__ kbf, const uint16_t* __restrict__ vbf_t,
    const uint16_t* __restrict__ qbf,
    float* __restrict__ upart, float* __restrict__ cpart) {
    __shared__ __align__(16) uint16_t als[8][1024];
    __shared__ __align__(16) float part[8][7][132];
    __shared__ float bsum[8][8];
    const int t = threadIdx.x, wv = t >> 6, lane = t & 63;
    const int lm = lane & 15, qd = lane >> 4;
    const int b = blockIdx.x >> 3, chunk = blockIdx.x & 7;
    const int rb = chunk * 512 + wv * 64;
    const long gbase = (long)b * N_ + rb;

    bf16x8 bq[4];
    #pragma unroll
    for (int k0 = 0; k0 < 4; ++k0)
        bq[k0] = *(const bf16x8*)(qbf + b * 2048 + lm * 128 + k0 * 32 + qd * 8);

    float csl = 0.f;
    #pragma unroll
    for (int mt = 0; mt < 4; ++mt) {
        f32x4 acc = {0.f, 0.f, 0.f, 0.f};
        long rr = gbase + mt * 16;
        #pragma unroll
        for (int k0 = 0; k0 < 4; ++k0) {
            bf16x8 a = *(const bf16x8*)(kbf + (rr + lm) * 128 + k0 * 32 + qd * 8);
            acc = __builtin_amdgcn_mfma_f32_16x16x32_bf16(a, bq[k0], acc, 0, 0, 0);
        }
        uint16_t pb[4];
        #pragma unroll
        for (int r = 0; r < 4; ++r) {
            float sc = acc[r];
            float scm = (lm < 7) ? sc : -1e30f;
            #pragma unroll
            for (int m = 1; m < 16; m <<= 1) scm = fmaxf(scm, __shfl_xor(scm, m));
            float e = (lm < 7) ? __expf(sc - scm) : 0.f;
            float tot = e;
            #pragma unroll
            for (int m = 1; m < 16; m <<= 1) tot += __shfl_xor(tot, m);
            float a_ = e / tot + EPS_;
            if (lm < 7) csl += a_;
            pb[r] = f2bfbits(a_);
        }
        int elem = (mt >> 1) * 512 + (((mt & 1) * 2 + (qd >> 1)) * 16 + lm) * 8 + (qd & 1) * 4;
        uint2 pw; pw.x = (uint32_t)pb[0] | ((uint32_t)pb[1] << 16);
        pw.y = (uint32_t)pb[2] | ((uint32_t)pb[3] << 16);
        *(uint2*)(&als[wv][elem]) = pw;
    }
    csl += __shfl_xor(csl, 16); csl += __shfl_xor(csl, 32);
    if (lane < 7) bsum[wv][lane] = csl;
    __syncthreads();

    bf16x8 afr0 = *(const bf16x8*)(&als[wv][lane * 8]);
    bf16x8 afr1 = *(const bf16x8*)(&als[wv][512 + lane * 8]);
    f32x4 uacc[8];
    #pragma unroll
    for (int i = 0; i < 8; ++i) uacc[i] = (f32x4){0.f, 0.f, 0.f, 0.f};
    #pragma unroll
    for (int nt = 0; nt < 8; ++nt) {
        const uint16_t* vp = vbf_t + ((long)(b * 128 + nt * 16 + lm)) * 4096 + rb;
        bf16x8 v0 = *(const bf16x8*)(vp + qd * 8);
        bf16x8 v1 = *(const bf16x8*)(vp + 32 + qd * 8);
        uacc[nt] = __builtin_amdgcn_mfma_f32_16x16x32_bf16(v0, afr0, uacc[nt], 0, 0, 0);
        uacc[nt] = __builtin_amdgcn_mfma_f32_16x16x32_bf16(v1, afr1, uacc[nt], 0, 0, 0);
    }
    if (lm < 7) {
        #pragma unroll
        for (int nt = 0; nt < 8; ++nt)
            *(f32x4*)&part[wv][lm][nt * 16 + qd * 4] = uacc[nt];
    }
    __syncthreads();
    if (t < 128) {
        #pragma unroll
        for (int s = 0; s < 7; ++s) {
            float v = 0.f;
            #pragma unroll
            for (int w = 0; w < 8; ++w) v += part[w][s][t];
            upart[((b * 8 + chunk) * 7 + s) * 128 + t] = v;
        }
    }
    if (t < 7) {
        float c = 0.f;
        #pragma unroll
        for (int w = 0; w < 8; ++w) c += bsum[w][t];
        cpart[(b * 8 + chunk) * 7 + t] = c;
    }
}

// ---------------------------------------------------------------------------
// K4 (fused, one block per batch b, 256 thr): reduce partials -> u; GRU via
// MFMA; LN; MLP via MFMA; write slots/dst; if hasq: LN + q-proj.
// ---------------------------------------------------------------------------
__global__ __launch_bounds__(256) void k_fused(
    const float* __restrict__ upart, const float* __restrict__ cpart,
    float* __restrict__ slots,
    const float* __restrict__ Wih, const float* __restrict__ Whh,
    const float* __restrict__ bih, const float* __restrict__ bhh,
    const float* __restrict__ gm, const float* __restrict__ bm,
    const float* __restrict__ W1, const float* __restrict__ b1,
    const float* __restrict__ W2, const float* __restrict__ b2,
    const float* __restrict__ Wq, const float* __restrict__ lsg,
    const float* __restrict__ lsb,
    uint16_t* __restrict__ qbf, float* __restrict__ dst, int hasq) {
    __shared__ float uf[16][132];
    __shared__ float hf[16][132];
    __shared__ float slf[16][132];
    __shared__ float hidl[16][264];
    __shared__ float glg[7][776];
    __shared__ float csl[7];
    const int b = blockIdx.x;
    const int t = threadIdx.x, wv = t >> 6, lane = t & 63;
    const int lm = lane & 15, qd = lane >> 4;

    if (t < 7) {
        float c = 0.f;
        #pragma unroll
        for (int i = 0; i < 8; ++i) c += cpart[(b * 8 + i) * 7 + t];
        csl[t] = c;
    }
    __syncthreads();
    for (int idx = t; idx < 896; idx += 256) {
        int s = idx >> 7, d = idx & 127;
        float acc = 0.f;
        #pragma unroll
        for (int i = 0; i < 8; ++i) acc += upart[((b * 8 + i) * 7 + s) * 128 + d];
        uf[s][d] = acc / csl[s];
        hf[s][d] = slots[(b * 7 + s) * 128 + d];
    }
    __syncthreads();

    bf16x8 au[4], ah[4];
    #pragma unroll
    for (int k0 = 0; k0 < 4; ++k0)
        #pragma unroll
        for (int j = 0; j < 8; ++j) {
            au[k0][j] = (__bf16)uf[lm][k0 * 32 + qd * 8 + j];
            ah[k0][j] = (__bf16)hf[lm][k0 * 32 + qd * 8 + j];
        }

    {
        const int ih = (wv < 2);
        const float* W = ih ? Wih : Whh;
        const int base = ih ? 0 : 384;
        const int w2 = wv & 1;
        #pragma unroll
        for (int i = 0; i < 12; ++i) {
            int o0 = (w2 * 12 + i) * 16;
            f32x4 acc = {0.f, 0.f, 0.f, 0.f};
            #pragma unroll
            for (int k0 = 0; k0 < 4; ++k0) {
                bf16x8 bf = ldfrag_w(W + (o0 + lm) * 128 + k0 * 32 + qd * 8);
                acc = __builtin_amdgcn_mfma_f32_16x16x32_bf16(ih ? au[k0] : ah[k0], bf, acc, 0, 0, 0);
            }
            #pragma unroll
            for (int r = 0; r < 4; ++r) {
                int s = qd * 4 + r;
                if (s < 7) glg[s][base + o0 + lm] = acc[r];
            }
        }
    }
    __syncthreads();

    for (int idx = t; idx < 896; idx += 256) {
        int s = idx >> 7, d = idx & 127;
        float xr = glg[s][d] + bih[d];
        float xz = glg[s][128 + d] + bih[128 + d];
        float xn = glg[s][256 + d] + bih[256 + d];
        float hr = glg[s][384 + d] + bhh[d];
        float hz = glg[s][512 + d] + bhh[128 + d];
        float hnn = glg[s][640 + d] + bhh[256 + d];
        float r = 1.f / (1.f + __expf(-(xr + hr)));
        float z = 1.f / (1.f + __expf(-(xz + hz)));
        float n = tanhf(xn + r * hnn);
        uf[s][d] = (1.f - z) * n + z * hf[s][d];
    }
    __syncthreads();

    for (int s = wv; s < 7; s += 4) {
        float a0 = uf[s][2 * lane], a1 = uf[s][2 * lane + 1];
        float sm = a0 + a1, sq = a0 * a0 + a1 * a1;
        #pragma unroll
        for (int m = 1; m < 64; m <<= 1) { sm += __shfl_xor(sm, m); sq += __shfl_xor(sq, m); }
        float mean = sm * (1.0f / 128.0f);
        float var = sq * (1.0f / 128.0f) - mean * mean;
        float rs = rsqrtf(var + LN_EPS_);
        slf[s][2 * lane]     = (a0 - mean) * rs * gm[2 * lane] + bm[2 * lane];
        slf[s][2 * lane + 1] = (a1 - mean) * rs * gm[2 * lane + 1] + bm[2 * lane + 1];
    }
    __syncthreads();

    bf16x8 as_[4];
    #pragma unroll
    for (int k0 = 0; k0 < 4; ++k0)
        #pragma unroll
        for (int j = 0; j < 8; ++j) as_[k0][j] = (__bf16)slf[lm][k0 * 32 + qd * 8 + j];
    #pragma unroll
    for (int i = 0; i < 4; ++i) {
        int o0 = (wv * 4 + i) * 16;
        f32x4 acc = {0.f, 0.f, 0.f, 0.f};
        #pragma unroll
        for (int k0 = 0; k0 < 4; ++k0) {
            bf16x8 bf = ldfrag_w(W1 + (o0 + lm) * 128 + k0 * 32 + qd * 8);
            acc = __builtin_amdgcn_mfma_f32_16x16x32_bf16(as_[k0], bf, acc, 0, 0, 0);
        }
        #pragma unroll
        for (int r = 0; r < 4; ++r) {
            int s = qd * 4 + r;
            if (s < 7) hidl[s][o0 + lm] = fmaxf(acc[r] + b1[o0 + lm], 0.f);
        }
    }
    __syncthreads();

    bf16x8 ahd[8];
    #pragma unroll
    for (int k0 = 0; k0 < 8; ++k0)
        #pragma unroll
        for (int j = 0; j < 8; ++j) ahd[k0][j] = (__bf16)hidl[lm][k0 * 32 + qd * 8 + j];
    #pragma unroll
    for (int i = 0; i < 2; ++i) {
        int o0 = (wv * 2 + i) * 16;
        f32x4 acc = {0.f, 0.f, 0.f, 0.f};
        #pragma unroll
        for (int k0 = 0; k0 < 8; ++k0) {
            bf16x8 bf = ldfrag_w(W2 + (o0 + lm) * 256 + k0 * 32 + qd * 8);
            acc = __builtin_amdgcn_mfma_f32_16x16x32_bf16(ahd[k0], bf, acc, 0, 0, 0);
        }
        #pragma unroll
        for (int r = 0; r < 4; ++r) {
            int s = qd * 4 + r;
            if (s < 7) {
                float v = slf[s][o0 + lm] + acc[r] + b2[o0 + lm];
                hf[s][o0 + lm] = v;
                dst[(b * 7 + s) * 128 + o0 + lm] = v;
            }
        }
    }
    if (hasq) {
        __syncthreads();
        for (int s = wv; s < 7; s += 4) {
            float a0 = hf[s][2 * lane], a1 = hf[s][2 * lane + 1];
            float sm = a0 + a1, sq = a0 * a0 + a1 * a1;
            #pragma unroll
            for (int m = 1; m < 64; m <<= 1) { sm += __shfl_xor(sm, m); sq += __shfl_xor(sq, m); }
            float mean = sm * (1.0f / 128.0f);
            float var = sq * (1.0f / 128.0f) - mean * mean;
            float rs = rsqrtf(var + LN_EPS_);
            uf[s][2 * lane]     = (a0 - mean) * rs * lsg[2 * lane] + lsb[2 * lane];
            uf[s][2 * lane + 1] = (a1 - mean) * rs * lsg[2 * lane + 1] + lsb[2 * lane + 1];
        }
        __syncthreads();
        bf16x8 an[4];
        #pragma unroll
        for (int k0 = 0; k0 < 4; ++k0)
            #pragma unroll
            for (int j = 0; j < 8; ++j) an[k0][j] = (__bf16)uf[lm][k0 * 32 + qd * 8 + j];
        #pragma unroll
        for (int i = 0; i < 2; ++i) {
            int o0 = (wv * 2 + i) * 16;
            f32x4 acc = {0.f, 0.f, 0.f, 0.f};
            #pragma unroll
            for (int k0 = 0; k0 < 4; ++k0) {
                bf16x8 bf = ldfrag_w(Wq + (o0 + lm) * 128 + k0 * 32 + qd * 8);
                acc = __builtin_amdgcn_mfma_f32_16x16x32_bf16(an[k0], bf, acc, 0, 0, 0);
            }
            #pragma unroll
            for (int r = 0; r < 4; ++r) {
                int s = qd * 4 + r;
                if (s < 7)
                    qbf[(b * 16 + s) * 128 + o0 + lm] = f2bfbits(acc[r] * 0.08838834764831843f);
            }
        }
    }
}

// ---------------------------------------------------------------------------
extern "C" void kernel_launch(void* const* d_in, const int* in_sizes, int n_in,
                              void* d_out, int out_size, void* d_ws, size_t ws_size,
                              hipStream_t stream) {
    const float* x    = (const float*)d_in[0];
    const float* nz   = (const float*)d_in[1];
    const float* Wq   = (const float*)d_in[2];
    const float* Wk   = (const float*)d_in[3];
    const float* Wv   = (const float*)d_in[4];
    const float* ling = (const float*)d_in[5];
    const float* linb = (const float*)d_in[6];
    const float* lsg  = (const float*)d_in[7];
    const float* lsb  = (const float*)d_in[8];
    const float* lmg  = (const float*)d_in[9];
    const float* lmb  = (const float*)d_in[10];
    const float* Wih  = (const float*)d_in[11];
    const float* Whh  = (const float*)d_in[12];
    const float* bih  = (const float*)d_in[13];
    const float* bhh  = (const float*)d_in[14];
    const float* W1   = (const float*)d_in[15];
    const float* b1   = (const float*)d_in[16];
    const float* W2   = (const float*)d_in[17];
    const float* b2   = (const float*)d_in[18];
    const float* mu   = (const float*)d_in[19];
    const float* lsig = (const float*)d_in[20];

    char* wsb = (char*)d_ws;
    uint16_t* kbf   = (uint16_t*)(wsb);                        // 67108864 B
    uint16_t* vbf_t = (uint16_t*)(wsb + (size_t)67108864);     // 67108864 B
    uint16_t* Wsw   = (uint16_t*)(wsb + (size_t)134217728);    // 65536 B
    uint16_t* qbf   = (uint16_t*)(wsb + (size_t)134283264);    // 262144 B
    float*    slots = (float*)  (wsb + (size_t)134545408);     // 229376 B
    float*    upart = (float*)  (wsb + (size_t)134774784);     // 1835008 B
    float*    cpart = (float*)  (wsb + (size_t)136609792);     // 14336 B

    k_prep<<<448, 256, 0, stream>>>(nz, Wk, Wv, mu, lsig, Wq, lsg, lsb,
                                    Wsw, slots, qbf);
    k_proj<<<2048, 512, 0, stream>>>(x, Wsw, ling, linb, kbf, vbf_t);
    for (int it = 0; it < 3; ++it) {
        float* dst = (it == 2) ? (float*)d_out : slots;
        k_attn<<<512, 512, 0, stream>>>(kbf, vbf_t, qbf, upart, cpart);
        k_fused<<<64, 256, 0, stream>>>(upart, cpart, slots, Wih, Whh, bih, bhh,
                                        lmg, lmb, W1, b1, W2, b2, Wq, lsg, lsb,
                                        qbf, dst, (it < 2) ? 1 : 0);
    }
}

// Round 5
// 414.318 us; speedup vs baseline: 1.0700x; 1.0700x over previous
//
#include <hip/hip_runtime.h>
#include <hip/hip_bf16.h>
#include <stdint.h>

#define B_ 64
#define N_ 4096
#define D_ 128
#define S_ 7
#define EPS_ 1e-8f
#define LN_EPS_ 1e-5f

typedef float  f32x4  __attribute__((ext_vector_type(4)));
typedef __bf16 bf16x8 __attribute__((ext_vector_type(8)));

// wbf (bf16 frag-linear GRU/MLP/Wq weights) segment offsets (elements)
#define WIH_OFF 0
#define WHH_OFF 49152
#define W1_OFF  98304
#define W2_OFF  131072
#define WQ_OFF  163840
#define WBF_TOT 180224

__device__ __forceinline__ uint16_t f2bfbits(float f) {
    uint32_t x = __float_as_uint(f);
    return (uint16_t)((x + 0x7fffu + ((x >> 16) & 1u)) >> 16);  // RNE
}
__device__ __forceinline__ uint32_t pk2(float a, float b) {
    return (uint32_t)f2bfbits(a) | ((uint32_t)f2bfbits(b) << 16);
}

// ---------------------------------------------------------------------------
// K0 (448 blocks x 256): block computes slots row (mu+scale*noise), LN,
// initial q-proj. Strided: Wsw swizzle, qbf pad zero, wbf (GRU/MLP/Wq) swizzle.
// ---------------------------------------------------------------------------
__global__ __launch_bounds__(256) void k_prep(
    const float* __restrict__ noise, const float* __restrict__ Wk,
    const float* __restrict__ Wv, const float* __restrict__ mu,
    const float* __restrict__ logsigma, const float* __restrict__ Wq,
    const float* __restrict__ lsg, const float* __restrict__ lsb,
    const float* __restrict__ Wih, const float* __restrict__ Whh,
    const float* __restrict__ W1, const float* __restrict__ W2,
    uint16_t* __restrict__ Wsw, float* __restrict__ slots,
    uint16_t* __restrict__ qbf, uint16_t* __restrict__ wbf) {
    const int t = threadIdx.x;
    const int tid = blockIdx.x * 256 + t;
    __shared__ float sn[128];
    __shared__ float red[2];
    {
        int row = blockIdx.x;  // < 448
        int b = row / 7, s = row - b * 7;
        bool act = t < 128;
        float v = 0.f;
        if (act) {
            float sc = log1pf(__expf(logsigma[t])) + 1e-5f;
            v = mu[t] + sc * noise[row * 128 + t];
            slots[row * 128 + t] = v;
        }
        float sv = act ? v : 0.f;
        #pragma unroll
        for (int m = 1; m < 64; m <<= 1) sv += __shfl_xor(sv, m);
        if (act && (t & 63) == 0) red[t >> 6] = sv;
        __syncthreads();
        float mean = (red[0] + red[1]) * (1.0f / 128.0f);
        __syncthreads();
        float dv = act ? (v - mean) : 0.f;
        float sq = dv * dv;
        #pragma unroll
        for (int m = 1; m < 64; m <<= 1) sq += __shfl_xor(sq, m);
        if (act && (t & 63) == 0) red[t >> 6] = sq;
        __syncthreads();
        float var = (red[0] + red[1]) * (1.0f / 128.0f);
        if (act) sn[t] = dv * rsqrtf(var + LN_EPS_) * lsg[t] + lsb[t];
        __syncthreads();
        if (act) {
            const float4* wr = (const float4*)(Wq + t * 128);
            float acc = 0.f;
            #pragma unroll 8
            for (int j = 0; j < 32; ++j) {
                float4 w = wr[j];
                float4 s4 = *(const float4*)(sn + 4 * j);
                acc += w.x * s4.x + w.y * s4.y + w.z * s4.z + w.w * s4.w;
            }
            qbf[(b * 16 + s) * 128 + t] = f2bfbits(acc * 0.08838834764831843f);
        }
    }
    if (tid < 32768) {  // [Wk;Wv] frag-linear for k_proj
        int j = tid & 7, ch = tid >> 3;
        int lane = ch & 63, k0 = (ch >> 6) & 3, wt = (ch >> 8) & 7, h = ch >> 11;
        int row = wt * 16 + (lane & 15);
        int col = k0 * 32 + (lane >> 4) * 8 + j;
        float w = h ? Wv[row * 128 + col] : Wk[row * 128 + col];
        Wsw[tid] = f2bfbits(w);
    }
    if (tid < 73728) {  // zero q pad rows s=7..15
        int bb = tid / 1152, rem = tid - bb * 1152;
        int s = 7 + (rem >> 7), d = rem & 127;
        qbf[(bb * 16 + s) * 128 + d] = 0;
    }
    // GRU/MLP/Wq weights -> bf16 frag-linear (B-operand layout)
    for (int e = tid; e < WBF_TOT; e += 448 * 256) {
        const float* W; int C, el;
        if (e < WHH_OFF)      { W = Wih; C = 128; el = e; }
        else if (e < W1_OFF)  { W = Whh; C = 128; el = e - WHH_OFF; }
        else if (e < W2_OFF)  { W = W1;  C = 128; el = e - W1_OFF; }
        else if (e < WQ_OFF)  { W = W2;  C = 256; el = e - W2_OFF; }
        else                  { W = Wq;  C = 128; el = e - WQ_OFF; }
        int tile = el >> 9, within = el & 511;
        int lp = within >> 3, j = within & 7;
        int lm = lp & 15, qd = lp >> 4;
        int ktN = C >> 5;
        int ot = tile / ktN, kt = tile - ot * ktN;
        wbf[e] = f2bfbits(W[(ot * 16 + lm) * C + kt * 32 + qd * 8 + j]);
    }
}

// ---------------------------------------------------------------------------
// K1: LN(x) in regs -> bf16 frags; K-half C=Wk*xn^T -> kfrag (frag-linear);
//     V-half C=xn*Wv^T -> vfrag (frag-linear). Stores land as contiguous
//     256 B segments per wave instruction. 256 thr / 4 waves / 64 rows.
// ---------------------------------------------------------------------------
__global__ __launch_bounds__(256) void k_proj(
    const float* __restrict__ x, const uint16_t* __restrict__ Wsw,
    const float* __restrict__ lng, const float* __restrict__ lnb,
    uint16_t* __restrict__ kfrag, uint16_t* __restrict__ vfrag) {
    __shared__ __align__(16) uint16_t wlds[16384];  // 32 KB, frag-linear
    const int t = threadIdx.x, wv = t >> 6, lane = t & 63;
    const int lm = lane & 15, qd = lane >> 4;
    const long row0 = (long)blockIdx.x * 64;
    const int b = (int)(row0 >> 12);
    const int nloc = (int)(row0 & 4095);

    uint4 wst[8];
    #pragma unroll
    for (int i = 0; i < 8; ++i)
        wst[i] = *(const uint4*)(Wsw + (i * 256 + t) * 8);

    const long xrow = row0 + wv * 16 + lm;
    const float* xp = x + xrow * 128 + qd * 8;
    f32x4 xa[8];
    #pragma unroll
    for (int k0 = 0; k0 < 4; ++k0) {
        xa[2 * k0]     = *(const f32x4*)(xp + k0 * 32);
        xa[2 * k0 + 1] = *(const f32x4*)(xp + k0 * 32 + 4);
    }
    #pragma unroll
    for (int i = 0; i < 8; ++i)
        *(uint4*)(wlds + (i * 256 + t) * 8) = wst[i];
    // prefetch half 1 while LN + K-half run
    #pragma unroll
    for (int i = 0; i < 8; ++i)
        wst[i] = *(const uint4*)(Wsw + 16384 + (i * 256 + t) * 8);

    float s = 0.f, sq = 0.f;
    #pragma unroll
    for (int i = 0; i < 8; ++i)
        #pragma unroll
        for (int c = 0; c < 4; ++c) { float v = xa[i][c]; s += v; sq += v * v; }
    s  += __shfl_xor(s, 16);  s  += __shfl_xor(s, 32);
    sq += __shfl_xor(sq, 16); sq += __shfl_xor(sq, 32);
    float mean = s * (1.0f / 128.0f);
    float var  = sq * (1.0f / 128.0f) - mean * mean;
    float rs   = rsqrtf(var + LN_EPS_);

    bf16x8 xf[4];
    #pragma unroll
    for (int k0 = 0; k0 < 4; ++k0) {
        const float* gp = lng + k0 * 32 + qd * 8;
        const float* bp = lnb + k0 * 32 + qd * 8;
        f32x4 g0 = *(const f32x4*)(gp), g1 = *(const f32x4*)(gp + 4);
        f32x4 b0 = *(const f32x4*)(bp), b1 = *(const f32x4*)(bp + 4);
        #pragma unroll
        for (int c = 0; c < 4; ++c) {
            xf[k0][c]     = (__bf16)((xa[2 * k0][c]     - mean) * rs * g0[c] + b0[c]);
            xf[k0][4 + c] = (__bf16)((xa[2 * k0 + 1][c] - mean) * rs * g1[c] + b1[c]);
        }
    }
    __syncthreads();  // wlds half0 ready

    // K-half: D[d][n]; lane holds d = mt*16+qd*4+r at n = row0+wv*16+lm
    const int ntg = (int)(row0 >> 4) + wv;  // global n-tile
    #pragma unroll
    for (int mt = 0; mt < 8; ++mt) {
        f32x4 acc = {0.f, 0.f, 0.f, 0.f};
        #pragma unroll
        for (int k0 = 0; k0 < 4; ++k0) {
            bf16x8 wf = *(const bf16x8*)(wlds + ((mt * 4 + k0) * 64 + lane) * 8);
            acc = __builtin_amdgcn_mfma_f32_16x16x32_bf16(wf, xf[k0], acc, 0, 0, 0);
        }
        uint2 st; st.x = pk2(acc[0], acc[1]); st.y = pk2(acc[2], acc[3]);
        long base = ((long)(ntg * 4 + (mt >> 1))) * 512
                  + (lm + 16 * ((2 * mt + (qd >> 1)) & 3)) * 8 + (qd & 1) * 4;
        *(uint2*)(kfrag + base) = st;
    }
    __syncthreads();  // wlds half0 reads done

    #pragma unroll
    for (int i = 0; i < 8; ++i)
        *(uint4*)(wlds + (i * 256 + t) * 8) = wst[i];
    __syncthreads();  // wlds half1 ready

    // V-half: D[n][d]; lane holds n = nloc+wv*16+qd*4+r at d = nt*16+lm
    #pragma unroll
    for (int nt = 0; nt < 8; ++nt) {
        f32x4 acc = {0.f, 0.f, 0.f, 0.f};
        #pragma unroll
        for (int k0 = 0; k0 < 4; ++k0) {
            bf16x8 wf = *(const bf16x8*)(wlds + ((nt * 4 + k0) * 64 + lane) * 8);
            acc = __builtin_amdgcn_mfma_f32_16x16x32_bf16(xf[k0], wf, acc, 0, 0, 0);
        }
        uint2 st; st.x = pk2(acc[0], acc[1]); st.y = pk2(acc[2], acc[3]);
        long tile = (long)(b * 8 + nt) * 128 + (nloc >> 5) + (wv >> 1);
        long base = tile * 512
                  + (lm + 16 * (((wv & 1) * 2 + (qd >> 1)) & 3)) * 8 + (qd & 1) * 4;
        *(uint2*)(vfrag + base) = st;
    }
}

// ---------------------------------------------------------------------------
// K3: scores (MFMA, A=kfrag coalesced) -> softmax S=7 -> bf16 attn frags in
//     LDS -> updates = v^T*attn (MFMA, A=vfrag coalesced) -> block partials.
// ---------------------------------------------------------------------------
__global__ __launch_bounds__(512) void k_attn(
    const uint16_t* __restrict__ kfrag, const uint16_t* __restrict__ vfrag,
    const uint16_t* __restrict__ qbf,
    float* __restrict__ upart, float* __restrict__ cpart) {
    __shared__ __align__(16) uint16_t als[8][1024];
    __shared__ __align__(16) float part[8][7][132];
    __shared__ float bsum[8][8];
    const int t = threadIdx.x, wv = t >> 6, lane = t & 63;
    const int lm = lane & 15, qd = lane >> 4;
    const int b = blockIdx.x >> 3, chunk = blockIdx.x & 7;
    const int rb = chunk * 512 + wv * 64;       // n base within batch
    const long gn = (long)b * N_ + rb;          // global n base (mult of 64)

    bf16x8 bq[4];
    #pragma unroll
    for (int k0 = 0; k0 < 4; ++k0)
        bq[k0] = *(const bf16x8*)(qbf + b * 2048 + lm * 128 + k0 * 32 + qd * 8);

    float csl = 0.f;
    #pragma unroll
    for (int mt = 0; mt < 4; ++mt) {
        f32x4 acc = {0.f, 0.f, 0.f, 0.f};
        long tb = ((gn >> 4) + mt) * 4;
        #pragma unroll
        for (int k0 = 0; k0 < 4; ++k0) {
            bf16x8 a = *(const bf16x8*)(kfrag + (tb + k0) * 512 + lane * 8);
            acc = __builtin_amdgcn_mfma_f32_16x16x32_bf16(a, bq[k0], acc, 0, 0, 0);
        }
        uint16_t pb[4];
        #pragma unroll
        for (int r = 0; r < 4; ++r) {
            float sc = acc[r];
            float scm = (lm < 7) ? sc : -1e30f;
            #pragma unroll
            for (int m = 1; m < 16; m <<= 1) scm = fmaxf(scm, __shfl_xor(scm, m));
            float e = (lm < 7) ? __expf(sc - scm) : 0.f;
            float tot = e;
            #pragma unroll
            for (int m = 1; m < 16; m <<= 1) tot += __shfl_xor(tot, m);
            float a_ = e / tot + EPS_;
            if (lm < 7) csl += a_;
            pb[r] = f2bfbits(a_);
        }
        int elem = (mt >> 1) * 512 + (((mt & 1) * 2 + (qd >> 1)) * 16 + lm) * 8 + (qd & 1) * 4;
        uint2 pw; pw.x = (uint32_t)pb[0] | ((uint32_t)pb[1] << 16);
        pw.y = (uint32_t)pb[2] | ((uint32_t)pb[3] << 16);
        *(uint2*)(&als[wv][elem]) = pw;
    }
    csl += __shfl_xor(csl, 16); csl += __shfl_xor(csl, 32);
    if (lane < 7) bsum[wv][lane] = csl;
    __syncthreads();

    bf16x8 afr0 = *(const bf16x8*)(&als[wv][lane * 8]);
    bf16x8 afr1 = *(const bf16x8*)(&als[wv][512 + lane * 8]);
    f32x4 uacc[8];
    #pragma unroll
    for (int i = 0; i < 8; ++i) uacc[i] = (f32x4){0.f, 0.f, 0.f, 0.f};
    #pragma unroll
    for (int nt = 0; nt < 8; ++nt) {
        long tb = ((long)(b * 8 + nt) * 128 + (rb >> 5)) * 512;
        bf16x8 v0 = *(const bf16x8*)(vfrag + tb + lane * 8);
        bf16x8 v1 = *(const bf16x8*)(vfrag + tb + 512 + lane * 8);
        uacc[nt] = __builtin_amdgcn_mfma_f32_16x16x32_bf16(v0, afr0, uacc[nt], 0, 0, 0);
        uacc[nt] = __builtin_amdgcn_mfma_f32_16x16x32_bf16(v1, afr1, uacc[nt], 0, 0, 0);
    }
    if (lm < 7) {
        #pragma unroll
        for (int nt = 0; nt < 8; ++nt)
            *(f32x4*)&part[wv][lm][nt * 16 + qd * 4] = uacc[nt];
    }
    __syncthreads();
    if (t < 128) {
        #pragma unroll
        for (int s = 0; s < 7; ++s) {
            float v = 0.f;
            #pragma unroll
            for (int w = 0; w < 8; ++w) v += part[w][s][t];
            upart[((b * 8 + chunk) * 7 + s) * 128 + t] = v;
        }
    }
    if (t < 7) {
        float c = 0.f;
        #pragma unroll
        for (int w = 0; w < 8; ++w) c += bsum[w][t];
        cpart[(b * 8 + chunk) * 7 + t] = c;
    }
}

// ---------------------------------------------------------------------------
// K4 (fused, one block per batch, 256 thr): reduce partials -> u; GRU via
// MFMA (frag-linear bf16 weights); LN; MLP via MFMA; write dst; opt. q-proj.
// ---------------------------------------------------------------------------
__global__ __launch_bounds__(256) void k_fused(
    const float* __restrict__ upart, const float* __restrict__ cpart,
    float* __restrict__ slots, const uint16_t* __restrict__ wbf,
    const float* __restrict__ bih, const float* __restrict__ bhh,
    const float* __restrict__ gm, const float* __restrict__ bm,
    const float* __restrict__ b1, const float* __restrict__ b2,
    const float* __restrict__ lsg, const float* __restrict__ lsb,
    uint16_t* __restrict__ qbf, float* __restrict__ dst, int hasq) {
    __shared__ float uf[16][132];
    __shared__ float hf[16][132];
    __shared__ float slf[16][132];
    __shared__ float hidl[16][264];
    __shared__ float glg[7][776];
    __shared__ float csl[7];
    const int b = blockIdx.x;
    const int t = threadIdx.x, wv = t >> 6, lane = t & 63;
    const int lm = lane & 15, qd = lane >> 4;

    if (t < 7) {
        float c = 0.f;
        #pragma unroll
        for (int i = 0; i < 8; ++i) c += cpart[(b * 8 + i) * 7 + t];
        csl[t] = c;
    }
    __syncthreads();
    for (int idx = t; idx < 896; idx += 256) {
        int s = idx >> 7, d = idx & 127;
        float acc = 0.f;
        #pragma unroll
        for (int i = 0; i < 8; ++i) acc += upart[((b * 8 + i) * 7 + s) * 128 + d];
        uf[s][d] = acc / csl[s];
        hf[s][d] = slots[(b * 7 + s) * 128 + d];
    }
    __syncthreads();

    bf16x8 au[4], ah[4];
    #pragma unroll
    for (int k0 = 0; k0 < 4; ++k0)
        #pragma unroll
        for (int j = 0; j < 8; ++j) {
            au[k0][j] = (__bf16)uf[lm][k0 * 32 + qd * 8 + j];
            ah[k0][j] = (__bf16)hf[lm][k0 * 32 + qd * 8 + j];
        }

    {
        const int ih = (wv < 2);
        const uint16_t* W = wbf + (ih ? WIH_OFF : WHH_OFF);
        const int base = ih ? 0 : 384;
        const int w2 = wv & 1;
        #pragma unroll
        for (int i = 0; i < 12; ++i) {
            int ot = w2 * 12 + i;
            f32x4 acc = {0.f, 0.f, 0.f, 0.f};
            #pragma unroll
            for (int k0 = 0; k0 < 4; ++k0) {
                bf16x8 bf = *(const bf16x8*)(W + ((ot * 4 + k0) << 9) + lane * 8);
                acc = __builtin_amdgcn_mfma_f32_16x16x32_bf16(ih ? au[k0] : ah[k0], bf, acc, 0, 0, 0);
            }
            #pragma unroll
            for (int r = 0; r < 4; ++r) {
                int s = qd * 4 + r;
                if (s < 7) glg[s][base + ot * 16 + lm] = acc[r];
            }
        }
    }
    __syncthreads();

    for (int idx = t; idx < 896; idx += 256) {
        int s = idx >> 7, d = idx & 127;
        float xr = glg[s][d] + bih[d];
        float xz = glg[s][128 + d] + bih[128 + d];
        float xn = glg[s][256 + d] + bih[256 + d];
        float hr = glg[s][384 + d] + bhh[d];
        float hz = glg[s][512 + d] + bhh[128 + d];
        float hnn = glg[s][640 + d] + bhh[256 + d];
        float r = 1.f / (1.f + __expf(-(xr + hr)));
        float z = 1.f / (1.f + __expf(-(xz + hz)));
        float n = tanhf(xn + r * hnn);
        uf[s][d] = (1.f - z) * n + z * hf[s][d];
    }
    __syncthreads();

    for (int s = wv; s < 7; s += 4) {
        float a0 = uf[s][2 * lane], a1 = uf[s][2 * lane + 1];
        float sm = a0 + a1, sq = a0 * a0 + a1 * a1;
        #pragma unroll
        for (int m = 1; m < 64; m <<= 1) { sm += __shfl_xor(sm, m); sq += __shfl_xor(sq, m); }
        float mean = sm * (1.0f / 128.0f);
        float var = sq * (1.0f / 128.0f) - mean * mean;
        float rs = rsqrtf(var + LN_EPS_);
        slf[s][2 * lane]     = (a0 - mean) * rs * gm[2 * lane] + bm[2 * lane];
        slf[s][2 * lane + 1] = (a1 - mean) * rs * gm[2 * lane + 1] + bm[2 * lane + 1];
    }
    __syncthreads();

    bf16x8 as_[4];
    #pragma unroll
    for (int k0 = 0; k0 < 4; ++k0)
        #pragma unroll
        for (int j = 0; j < 8; ++j) as_[k0][j] = (__bf16)slf[lm][k0 * 32 + qd * 8 + j];
    #pragma unroll
    for (int i = 0; i < 4; ++i) {
        int ot = wv * 4 + i;
        f32x4 acc = {0.f, 0.f, 0.f, 0.f};
        #pragma unroll
        for (int k0 = 0; k0 < 4; ++k0) {
            bf16x8 bf = *(const bf16x8*)(wbf + W1_OFF + ((ot * 4 + k0) << 9) + lane * 8);
            acc = __builtin_amdgcn_mfma_f32_16x16x32_bf16(as_[k0], bf, acc, 0, 0, 0);
        }
        #pragma unroll
        for (int r = 0; r < 4; ++r) {
            int s = qd * 4 + r;
            if (s < 7) hidl[s][ot * 16 + lm] = fmaxf(acc[r] + b1[ot * 16 + lm], 0.f);
        }
    }
    __syncthreads();

    bf16x8 ahd[8];
    #pragma unroll
    for (int k0 = 0; k0 < 8; ++k0)
        #pragma unroll
        for (int j = 0; j < 8; ++j) ahd[k0][j] = (__bf16)hidl[lm][k0 * 32 + qd * 8 + j];
    #pragma unroll
    for (int i = 0; i < 2; ++i) {
        int ot = wv * 2 + i;
        f32x4 acc = {0.f, 0.f, 0.f, 0.f};
        #pragma unroll
        for (int k0 = 0; k0 < 8; ++k0) {
            bf16x8 bf = *(const bf16x8*)(wbf + W2_OFF + ((ot * 8 + k0) << 9) + lane * 8);
            acc = __builtin_amdgcn_mfma_f32_16x16x32_bf16(ahd[k0], bf, acc, 0, 0, 0);
        }
        #pragma unroll
        for (int r = 0; r < 4; ++r) {
            int s = qd * 4 + r;
            if (s < 7) {
                float v = slf[s][ot * 16 + lm] + acc[r] + b2[ot * 16 + lm];
                hf[s][ot * 16 + lm] = v;
                dst[(b * 7 + s) * 128 + ot * 16 + lm] = v;
            }
        }
    }
    if (hasq) {
        __syncthreads();
        for (int s = wv; s < 7; s += 4) {
            float a0 = hf[s][2 * lane], a1 = hf[s][2 * lane + 1];
            float sm = a0 + a1, sq = a0 * a0 + a1 * a1;
            #pragma unroll
            for (int m = 1; m < 64; m <<= 1) { sm += __shfl_xor(sm, m); sq += __shfl_xor(sq, m); }
            float mean = sm * (1.0f / 128.0f);
            float var = sq * (1.0f / 128.0f) - mean * mean;
            float rs = rsqrtf(var + LN_EPS_);
            uf[s][2 * lane]     = (a0 - mean) * rs * lsg[2 * lane] + lsb[2 * lane];
            uf[s][2 * lane + 1] = (a1 - mean) * rs * lsg[2 * lane + 1] + lsb[2 * lane + 1];
        }
        __syncthreads();
        bf16x8 an[4];
        #pragma unroll
        for (int k0 = 0; k0 < 4; ++k0)
            #pragma unroll
            for (int j = 0; j < 8; ++j) an[k0][j] = (__bf16)uf[lm][k0 * 32 + qd * 8 + j];
        #pragma unroll
        for (int i = 0; i < 2; ++i) {
            int ot = wv * 2 + i;
            f32x4 acc = {0.f, 0.f, 0.f, 0.f};
            #pragma unroll
            for (int k0 = 0; k0 < 4; ++k0) {
                bf16x8 bf = *(const bf16x8*)(wbf + WQ_OFF + ((ot * 4 + k0) << 9) + lane * 8);
                acc = __builtin_amdgcn_mfma_f32_16x16x32_bf16(an[k0], bf, acc, 0, 0, 0);
            }
            #pragma unroll
            for (int r = 0; r < 4; ++r) {
                int s = qd * 4 + r;
                if (s < 7)
                    qbf[(b * 16 + s) * 128 + ot * 16 + lm] = f2bfbits(acc[r] * 0.08838834764831843f);
            }
        }
    }
}

// ---------------------------------------------------------------------------
extern "C" void kernel_launch(void* const* d_in, const int* in_sizes, int n_in,
                              void* d_out, int out_size, void* d_ws, size_t ws_size,
                              hipStream_t stream) {
    const float* x    = (const float*)d_in[0];
    const float* nz   = (const float*)d_in[1];
    const float* Wq   = (const float*)d_in[2];
    const float* Wk   = (const float*)d_in[3];
    const float* Wv   = (const float*)d_in[4];
    const float* ling = (const float*)d_in[5];
    const float* linb = (const float*)d_in[6];
    const float* lsg  = (const float*)d_in[7];
    const float* lsb  = (const float*)d_in[8];
    const float* lmg  = (const float*)d_in[9];
    const float* lmb  = (const float*)d_in[10];
    const float* Wih  = (const float*)d_in[11];
    const float* Whh  = (const float*)d_in[12];
    const float* bih  = (const float*)d_in[13];
    const float* bhh  = (const float*)d_in[14];
    const float* W1   = (const float*)d_in[15];
    const float* b1   = (const float*)d_in[16];
    const float* W2   = (const float*)d_in[17];
    const float* b2   = (const float*)d_in[18];
    const float* mu   = (const float*)d_in[19];
    const float* lsig = (const float*)d_in[20];

    char* wsb = (char*)d_ws;
    uint16_t* kfrag = (uint16_t*)(wsb);                        // 67108864 B
    uint16_t* vfrag = (uint16_t*)(wsb + (size_t)67108864);     // 67108864 B
    uint16_t* Wsw   = (uint16_t*)(wsb + (size_t)134217728);    // 65536 B
    uint16_t* qbf   = (uint16_t*)(wsb + (size_t)134283264);    // 262144 B
    float*    slots = (float*)  (wsb + (size_t)134545408);     // 229376 B
    float*    upart = (float*)  (wsb + (size_t)134774784);     // 1835008 B
    float*    cpart = (float*)  (wsb + (size_t)136609792);     // 14336 B
    uint16_t* wbf   = (uint16_t*)(wsb + (size_t)136624128);    // 360448 B

    k_prep<<<448, 256, 0, stream>>>(nz, Wk, Wv, mu, lsig, Wq, lsg, lsb,
                                    Wih, Whh, W1, W2, Wsw, slots, qbf, wbf);
    k_proj<<<4096, 256, 0, stream>>>(x, Wsw, ling, linb, kfrag, vfrag);
    for (int it = 0; it < 3; ++it) {
        float* dst = (it == 2) ? (float*)d_out : slots;
        k_attn<<<512, 512, 0, stream>>>(kfrag, vfrag, qbf, upart, cpart);
        k_fused<<<64, 256, 0, stream>>>(upart, cpart, slots, wbf, bih, bhh,
                                        lmg, lmb, b1, b2, lsg, lsb,
                                        qbf, dst, (it < 2) ? 1 : 0);
    }
}

// Round 6
// 376.098 us; speedup vs baseline: 1.1787x; 1.1016x over previous
//
#include <hip/hip_runtime.h>
#include <hip/hip_bf16.h>
#include <stdint.h>

#define B_ 64
#define N_ 4096
#define D_ 128
#define S_ 7
#define EPS_ 1e-8f
#define LN_EPS_ 1e-5f
#define SC_INV 0.08838834764831843f  // 1/sqrt(128)

typedef float  f32x4  __attribute__((ext_vector_type(4)));
typedef __bf16 bf16x8 __attribute__((ext_vector_type(8)));

// wbf (bf16 frag-linear weights) segment offsets (elements)
#define WIH_OFF 0
#define WHH_OFF 49152
#define W1_OFF  98304
#define W2_OFF  131072
#define WQ_OFF  163840
#define WKT_OFF 180224
#define WV_OFF  196608
#define WBF_TOT 212992

__device__ __forceinline__ uint16_t f2bfbits(float f) {
    uint32_t x = __float_as_uint(f);
    return (uint16_t)((x + 0x7fffu + ((x >> 16) & 1u)) >> 16);  // RNE
}
__device__ __forceinline__ uint32_t pk2(float a, float b) {
    return (uint32_t)f2bfbits(a) | ((uint32_t)f2bfbits(b) << 16);
}

// ---------------------------------------------------------------------------
// K0 (448 blocks x 256, one per (b,s)): slots row init, LN, q (fp32 dots),
// kq row = q@Wk * SC -> kqbf frag-linear; strided: kqbf pad-row zero + wbf
// swizzle (bf16 frag-linear weights for k_fused).
// ---------------------------------------------------------------------------
__global__ __launch_bounds__(256) void k_init(
    const float* __restrict__ noise, const float* __restrict__ Wk,
    const float* __restrict__ mu, const float* __restrict__ logsigma,
    const float* __restrict__ Wq, const float* __restrict__ lsg,
    const float* __restrict__ lsb,
    const float* __restrict__ Wih, const float* __restrict__ Whh,
    const float* __restrict__ W1, const float* __restrict__ W2,
    const float* __restrict__ Wv,
    float* __restrict__ slots, uint16_t* __restrict__ kqbf,
    uint16_t* __restrict__ wbf) {
    const int t = threadIdx.x;
    const int tid = blockIdx.x * 256 + t;
    const int row = blockIdx.x;           // b*7+s
    const int b = row / 7, s = row - b * 7;
    __shared__ float sn[128], qr[128];
    __shared__ float red[2];
    bool act = t < 128;
    float v = 0.f;
    if (act) {
        float sc = log1pf(__expf(logsigma[t])) + 1e-5f;
        v = mu[t] + sc * noise[row * 128 + t];
        slots[row * 128 + t] = v;
    }
    float sv = act ? v : 0.f;
    #pragma unroll
    for (int m = 1; m < 64; m <<= 1) sv += __shfl_xor(sv, m);
    if (act && (t & 63) == 0) red[t >> 6] = sv;
    __syncthreads();
    float mean = (red[0] + red[1]) * (1.0f / 128.0f);
    __syncthreads();
    float dv = act ? (v - mean) : 0.f;
    float sq = dv * dv;
    #pragma unroll
    for (int m = 1; m < 64; m <<= 1) sq += __shfl_xor(sq, m);
    if (act && (t & 63) == 0) red[t >> 6] = sq;
    __syncthreads();
    float var = (red[0] + red[1]) * (1.0f / 128.0f);
    if (act) sn[t] = dv * rsqrtf(var + LN_EPS_) * lsg[t] + lsb[t];
    __syncthreads();
    if (act) {
        const float4* wr = (const float4*)(Wq + t * 128);
        float acc = 0.f;
        #pragma unroll 8
        for (int j = 0; j < 32; ++j) {
            float4 w = wr[j];
            float4 s4 = *(const float4*)(sn + 4 * j);
            acc += w.x * s4.x + w.y * s4.y + w.z * s4.z + w.w * s4.w;
        }
        qr[t] = acc;
    }
    __syncthreads();
    if (act) {
        float kq = 0.f;
        #pragma unroll 8
        for (int o = 0; o < 128; ++o) kq += qr[o] * Wk[o * 128 + t];
        int elem = (t >> 5) * 512 + (s + 16 * ((t >> 3) & 3)) * 8 + (t & 7);
        kqbf[b * 2048 + elem] = f2bfbits(kq * SC_INV);
    }
    if (tid < 73728) {  // zero kq pad rows s'=7..15
        int bb = tid / 1152, rem = tid - bb * 1152;
        int sp = 7 + (rem >> 7), d = rem & 127;
        int elem = (d >> 5) * 512 + (sp + 16 * ((d >> 3) & 3)) * 8 + (d & 7);
        kqbf[bb * 2048 + elem] = 0;
    }
    for (int e = tid; e < WBF_TOT; e += 448 * 256) {
        const float* W; int C, el, mode = 0;
        if (e < WHH_OFF)      { W = Wih; C = 128; el = e; }
        else if (e < W1_OFF)  { W = Whh; C = 128; el = e - WHH_OFF; }
        else if (e < W2_OFF)  { W = W1;  C = 128; el = e - W1_OFF; }
        else if (e < WQ_OFF)  { W = W2;  C = 256; el = e - W2_OFF; }
        else if (e < WKT_OFF) { W = Wq;  C = 128; el = e - WQ_OFF; }
        else if (e < WV_OFF)  { W = Wk;  C = 128; el = e - WKT_OFF; mode = 1; }
        else                  { W = Wv;  C = 128; el = e - WV_OFF; }
        int tile = el >> 9, within = el & 511;
        int lp = within >> 3, j = within & 7;
        int lm_ = lp & 15, qd_ = lp >> 4;
        float w;
        if (!mode) {
            int ktN = C >> 5, ot = tile / ktN, kt = tile - ot * ktN;
            w = W[(ot * 16 + lm_) * C + kt * 32 + qd_ * 8 + j];
        } else {  // Wk non-transposed: B[k=o][col=d']
            int dt = tile >> 2, kt = tile & 3;
            w = W[(kt * 32 + qd_ * 8 + j) * 128 + dt * 16 + lm_];
        }
        wbf[e] = f2bfbits(w);
    }
}

// ---------------------------------------------------------------------------
// K1: pure streaming: xn = LN(x) -> bf16, stored MFMA frag-linear
//     (tile = ntile*4+kt; within: elem=lane*8+j <-> [n=lm][d=kt*32+qd*8+j]).
//     4 waves x 16 rows = 64 rows/block; no LDS.
// ---------------------------------------------------------------------------
__global__ __launch_bounds__(256) void k_prep_xn(
    const float* __restrict__ x, const float* __restrict__ lng,
    const float* __restrict__ lnb, uint16_t* __restrict__ xn) {
    const int t = threadIdx.x, wv = t >> 6, lane = t & 63;
    const int lm = lane & 15, qd = lane >> 4;
    const long row = (long)blockIdx.x * 64 + wv * 16 + lm;
    const long ntile = (long)blockIdx.x * 4 + wv;
    const float* xp = x + row * 128 + qd * 4;
    f32x4 xa[8];
    #pragma unroll
    for (int c = 0; c < 8; ++c) xa[c] = *(const f32x4*)(xp + c * 16);
    float s = 0.f, sq = 0.f;
    #pragma unroll
    for (int c = 0; c < 8; ++c)
        #pragma unroll
        for (int r = 0; r < 4; ++r) { float v = xa[c][r]; s += v; sq += v * v; }
    s  += __shfl_xor(s, 16);  s  += __shfl_xor(s, 32);
    sq += __shfl_xor(sq, 16); sq += __shfl_xor(sq, 32);
    float mean = s * (1.0f / 128.0f);
    float var  = sq * (1.0f / 128.0f) - mean * mean;
    float rs   = rsqrtf(var + LN_EPS_);
    #pragma unroll
    for (int c = 0; c < 8; ++c) {
        f32x4 g  = *(const f32x4*)(lng + c * 16 + qd * 4);
        f32x4 bb = *(const f32x4*)(lnb + c * 16 + qd * 4);
        float v0 = (xa[c][0] - mean) * rs * g[0] + bb[0];
        float v1 = (xa[c][1] - mean) * rs * g[1] + bb[1];
        float v2 = (xa[c][2] - mean) * rs * g[2] + bb[2];
        float v3 = (xa[c][3] - mean) * rs * g[3] + bb[3];
        uint2 st; st.x = pk2(v0, v1); st.y = pk2(v2, v3);
        long elem = (ntile * 4 + (c >> 1)) * 512
                  + (lm + 16 * (2 * (c & 1) + (qd >> 1))) * 8 + 4 * (qd & 1);
        *(uint2*)(xn + elem) = st;
    }
}

// ---------------------------------------------------------------------------
// K2 per iter: scores = xn·kq^T (MFMA, xn frags coalesced) -> softmax S=7 ->
// attn frags (als LDS) -> P += attn^T·xn (MFMA; xn^T frags via per-wave LDS
// transpose, pitch 132) -> per-block partials. 4 waves x 64 n; grid b*16.
// ---------------------------------------------------------------------------
__global__ __launch_bounds__(256) void k_attn(
    const uint16_t* __restrict__ xn, const uint16_t* __restrict__ kqbf,
    float* __restrict__ upart, float* __restrict__ cpart) {
    __shared__ __align__(16) uint16_t xns[4][32 * 132];  // per-wave transpose stage
    __shared__ __align__(16) uint16_t als[4][512];       // per-wave attn frags
    __shared__ float part[4][7][132];
    __shared__ float bsum[4][8];
    const int t = threadIdx.x, wv = t >> 6, lane = t & 63;
    const int lm = lane & 15, qd = lane >> 4;
    const int b = blockIdx.x >> 4, chunk = blockIdx.x & 15;
    const int ntb = b * 256 + chunk * 16 + wv * 4;  // global 16-row tile base

    bf16x8 kqf[4];
    #pragma unroll
    for (int k0 = 0; k0 < 4; ++k0)
        kqf[k0] = *(const bf16x8*)(kqbf + b * 2048 + k0 * 512 + lane * 8);

    uint16_t* xw = xns[wv];
    f32x4 uacc[8];
    #pragma unroll
    for (int i = 0; i < 8; ++i) uacc[i] = (f32x4){0.f, 0.f, 0.f, 0.f};
    float csl = 0.f;

    #pragma unroll
    for (int sub = 0; sub < 2; ++sub) {
        bf16x8 xf[2][4];
        #pragma unroll
        for (int nt = 0; nt < 2; ++nt)
            #pragma unroll
            for (int k0 = 0; k0 < 4; ++k0)
                xf[nt][k0] = *(const bf16x8*)(xn +
                    ((long)(ntb + sub * 2 + nt) * 4 + k0) * 512 + lane * 8);
        // stage to LDS n-major (for the transposed PV operand)
        #pragma unroll
        for (int nt = 0; nt < 2; ++nt)
            #pragma unroll
            for (int k0 = 0; k0 < 4; ++k0) {
                int base = (nt * 16 + lm) * 132 + k0 * 32 + qd * 8;
                const uint2* src = (const uint2*)&xf[nt][k0];
                *(uint2*)(xw + base)     = src[0];
                *(uint2*)(xw + base + 4) = src[1];
            }
        // scores + softmax + pack
        #pragma unroll
        for (int mt = 0; mt < 2; ++mt) {
            f32x4 acc = {0.f, 0.f, 0.f, 0.f};
            #pragma unroll
            for (int k0 = 0; k0 < 4; ++k0)
                acc = __builtin_amdgcn_mfma_f32_16x16x32_bf16(xf[mt][k0], kqf[k0], acc, 0, 0, 0);
            uint16_t pb[4];
            #pragma unroll
            for (int r = 0; r < 4; ++r) {
                float sc = acc[r];
                float scm = (lm < 7) ? sc : -1e30f;
                #pragma unroll
                for (int m = 1; m < 16; m <<= 1) scm = fmaxf(scm, __shfl_xor(scm, m));
                float e = (lm < 7) ? __expf(sc - scm) : 0.f;
                float tot = e;
                #pragma unroll
                for (int m = 1; m < 16; m <<= 1) tot += __shfl_xor(tot, m);
                float a_ = e / tot + EPS_;
                if (lm < 7) csl += a_;
                pb[r] = f2bfbits(a_);
            }
            int elem = (lm + 16 * (2 * mt + (qd >> 1))) * 8 + 4 * (qd & 1);
            uint2 pw; pw.x = (uint32_t)pb[0] | ((uint32_t)pb[1] << 16);
            pw.y = (uint32_t)pb[2] | ((uint32_t)pb[3] << 16);
            *(uint2*)(&als[wv][elem]) = pw;
        }
        // PV: A = attn^T frag, B = xn^T frag from LDS
        bf16x8 afr = *(const bf16x8*)(&als[wv][lane * 8]);
        #pragma unroll
        for (int dt = 0; dt < 8; ++dt) {
            bf16x8 bfr;
            #pragma unroll
            for (int j = 0; j < 8; ++j)
                bfr[j] = ((const __bf16*)xw)[(qd * 8 + j) * 132 + dt * 16 + lm];
            uacc[dt] = __builtin_amdgcn_mfma_f32_16x16x32_bf16(afr, bfr, uacc[dt], 0, 0, 0);
        }
    }
    csl += __shfl_xor(csl, 16); csl += __shfl_xor(csl, 32);
    if (lane < 7) bsum[wv][lane] = csl;
    #pragma unroll
    for (int dt = 0; dt < 8; ++dt)
        #pragma unroll
        for (int r = 0; r < 4; ++r) {
            int s = qd * 4 + r;
            if (s < 7) part[wv][s][dt * 16 + lm] = uacc[dt][r];
        }
    __syncthreads();
    if (t < 128) {
        #pragma unroll
        for (int s = 0; s < 7; ++s) {
            float v = part[0][s][t] + part[1][s][t] + part[2][s][t] + part[3][s][t];
            upart[((b * 16 + chunk) * 7 + s) * 128 + t] = v;
        }
    }
    if (t < 7)
        cpart[(b * 16 + chunk) * 7 + t] = bsum[0][t] + bsum[1][t] + bsum[2][t] + bsum[3][t];
}

// ---------------------------------------------------------------------------
// K3 (one block per batch, 256 thr): P = reduce(upart); u = (P@Wv^T)/csum via
// MFMA; GRU via MFMA; LN; MLP via MFMA; dst; if hasq: LN + q + kq -> kqbf.
// ---------------------------------------------------------------------------
__global__ __launch_bounds__(256) void k_fused(
    const float* __restrict__ upart, const float* __restrict__ cpart,
    float* __restrict__ slots, const uint16_t* __restrict__ wbf,
    const float* __restrict__ bih, const float* __restrict__ bhh,
    const float* __restrict__ gm, const float* __restrict__ bm,
    const float* __restrict__ b1, const float* __restrict__ b2,
    const float* __restrict__ lsg, const float* __restrict__ lsb,
    uint16_t* __restrict__ kqbf, float* __restrict__ dst, int hasq) {
    __shared__ float uf[16][132];     // u, then hn, then sn(for q)
    __shared__ float hf[16][132];     // h, then out
    __shared__ float slf[16][132];    // P, then LN(hn), then q
    __shared__ float hidl[16][264];   // MLP hidden, then kq
    __shared__ float glg[7][776];
    __shared__ float csl[7];
    const int b = blockIdx.x;
    const int t = threadIdx.x, wv = t >> 6, lane = t & 63;
    const int lm = lane & 15, qd = lane >> 4;

    if (t < 7) {
        float c = 0.f;
        #pragma unroll
        for (int i = 0; i < 16; ++i) c += cpart[(b * 16 + i) * 7 + t];
        csl[t] = c;
    }
    for (int idx = t; idx < 896; idx += 256) {
        int s = idx >> 7, d = idx & 127;
        float acc = 0.f;
        #pragma unroll
        for (int i = 0; i < 16; ++i) acc += upart[((b * 16 + i) * 7 + s) * 128 + d];
        slf[s][d] = acc;                       // P (pre-Wv, pre-renorm)
        hf[s][d] = slots[(b * 7 + s) * 128 + d];
    }
    __syncthreads();

    // u = (P @ Wv^T) / csum
    {
        bf16x8 apb[4];
        #pragma unroll
        for (int k0 = 0; k0 < 4; ++k0)
            #pragma unroll
            for (int j = 0; j < 8; ++j) apb[k0][j] = (__bf16)slf[lm][k0 * 32 + qd * 8 + j];
        #pragma unroll
        for (int i = 0; i < 2; ++i) {
            int dt = wv * 2 + i;
            f32x4 acc = {0.f, 0.f, 0.f, 0.f};
            #pragma unroll
            for (int k0 = 0; k0 < 4; ++k0) {
                bf16x8 bf = *(const bf16x8*)(wbf + WV_OFF + ((dt * 4 + k0) << 9) + lane * 8);
                acc = __builtin_amdgcn_mfma_f32_16x16x32_bf16(apb[k0], bf, acc, 0, 0, 0);
            }
            #pragma unroll
            for (int r = 0; r < 4; ++r) {
                int s = qd * 4 + r;
                if (s < 7) uf[s][dt * 16 + lm] = acc[r] / csl[s];
            }
        }
    }
    __syncthreads();

    bf16x8 au[4], ah[4];
    #pragma unroll
    for (int k0 = 0; k0 < 4; ++k0)
        #pragma unroll
        for (int j = 0; j < 8; ++j) {
            au[k0][j] = (__bf16)uf[lm][k0 * 32 + qd * 8 + j];
            ah[k0][j] = (__bf16)hf[lm][k0 * 32 + qd * 8 + j];
        }
    {
        const int ih = (wv < 2);
        const uint16_t* W = wbf + (ih ? WIH_OFF : WHH_OFF);
        const int base = ih ? 0 : 384;
        const int w2 = wv & 1;
        #pragma unroll
        for (int i = 0; i < 12; ++i) {
            int ot = w2 * 12 + i;
            f32x4 acc = {0.f, 0.f, 0.f, 0.f};
            #pragma unroll
            for (int k0 = 0; k0 < 4; ++k0) {
                bf16x8 bf = *(const bf16x8*)(W + ((ot * 4 + k0) << 9) + lane * 8);
                acc = __builtin_amdgcn_mfma_f32_16x16x32_bf16(ih ? au[k0] : ah[k0], bf, acc, 0, 0, 0);
            }
            #pragma unroll
            for (int r = 0; r < 4; ++r) {
                int s = qd * 4 + r;
                if (s < 7) glg[s][base + ot * 16 + lm] = acc[r];
            }
        }
    }
    __syncthreads();

    for (int idx = t; idx < 896; idx += 256) {
        int s = idx >> 7, d = idx & 127;
        float xr = glg[s][d] + bih[d];
        float xz = glg[s][128 + d] + bih[128 + d];
        float xg = glg[s][256 + d] + bih[256 + d];
        float hr = glg[s][384 + d] + bhh[d];
        float hz = glg[s][512 + d] + bhh[128 + d];
        float hg = glg[s][640 + d] + bhh[256 + d];
        float r = 1.f / (1.f + __expf(-(xr + hr)));
        float z = 1.f / (1.f + __expf(-(xz + hz)));
        float n = tanhf(xg + r * hg);
        uf[s][d] = (1.f - z) * n + z * hf[s][d];
    }
    __syncthreads();

    for (int s = wv; s < 7; s += 4) {
        float a0 = uf[s][2 * lane], a1 = uf[s][2 * lane + 1];
        float sm = a0 + a1, sq = a0 * a0 + a1 * a1;
        #pragma unroll
        for (int m = 1; m < 64; m <<= 1) { sm += __shfl_xor(sm, m); sq += __shfl_xor(sq, m); }
        float mean = sm * (1.0f / 128.0f);
        float var = sq * (1.0f / 128.0f) - mean * mean;
        float rs = rsqrtf(var + LN_EPS_);
        slf[s][2 * lane]     = (a0 - mean) * rs * gm[2 * lane] + bm[2 * lane];
        slf[s][2 * lane + 1] = (a1 - mean) * rs * gm[2 * lane + 1] + bm[2 * lane + 1];
    }
    __syncthreads();

    bf16x8 as_[4];
    #pragma unroll
    for (int k0 = 0; k0 < 4; ++k0)
        #pragma unroll
        for (int j = 0; j < 8; ++j) as_[k0][j] = (__bf16)slf[lm][k0 * 32 + qd * 8 + j];
    #pragma unroll
    for (int i = 0; i < 4; ++i) {
        int ot = wv * 4 + i;
        f32x4 acc = {0.f, 0.f, 0.f, 0.f};
        #pragma unroll
        for (int k0 = 0; k0 < 4; ++k0) {
            bf16x8 bf = *(const bf16x8*)(wbf + W1_OFF + ((ot * 4 + k0) << 9) + lane * 8);
            acc = __builtin_amdgcn_mfma_f32_16x16x32_bf16(as_[k0], bf, acc, 0, 0, 0);
        }
        #pragma unroll
        for (int r = 0; r < 4; ++r) {
            int s = qd * 4 + r;
            if (s < 7) hidl[s][ot * 16 + lm] = fmaxf(acc[r] + b1[ot * 16 + lm], 0.f);
        }
    }
    __syncthreads();

    bf16x8 ahd[8];
    #pragma unroll
    for (int k0 = 0; k0 < 8; ++k0)
        #pragma unroll
        for (int j = 0; j < 8; ++j) ahd[k0][j] = (__bf16)hidl[lm][k0 * 32 + qd * 8 + j];
    #pragma unroll
    for (int i = 0; i < 2; ++i) {
        int ot = wv * 2 + i;
        f32x4 acc = {0.f, 0.f, 0.f, 0.f};
        #pragma unroll
        for (int k0 = 0; k0 < 8; ++k0) {
            bf16x8 bf = *(const bf16x8*)(wbf + W2_OFF + ((ot * 8 + k0) << 9) + lane * 8);
            acc = __builtin_amdgcn_mfma_f32_16x16x32_bf16(ahd[k0], bf, acc, 0, 0, 0);
        }
        #pragma unroll
        for (int r = 0; r < 4; ++r) {
            int s = qd * 4 + r;
            if (s < 7) {
                float v = slf[s][ot * 16 + lm] + acc[r] + b2[ot * 16 + lm];
                hf[s][ot * 16 + lm] = v;
                dst[(b * 7 + s) * 128 + ot * 16 + lm] = v;
            }
        }
    }
    if (hasq) {
        __syncthreads();
        // sn = LN_slots(out) -> uf
        for (int s = wv; s < 7; s += 4) {
            float a0 = hf[s][2 * lane], a1 = hf[s][2 * lane + 1];
            float sm = a0 + a1, sq = a0 * a0 + a1 * a1;
            #pragma unroll
            for (int m = 1; m < 64; m <<= 1) { sm += __shfl_xor(sm, m); sq += __shfl_xor(sq, m); }
            float mean = sm * (1.0f / 128.0f);
            float var = sq * (1.0f / 128.0f) - mean * mean;
            float rs = rsqrtf(var + LN_EPS_);
            uf[s][2 * lane]     = (a0 - mean) * rs * lsg[2 * lane] + lsb[2 * lane];
            uf[s][2 * lane + 1] = (a1 - mean) * rs * lsg[2 * lane + 1] + lsb[2 * lane + 1];
        }
        __syncthreads();
        // q = sn @ Wq^T -> slf
        bf16x8 an[4];
        #pragma unroll
        for (int k0 = 0; k0 < 4; ++k0)
            #pragma unroll
            for (int j = 0; j < 8; ++j) an[k0][j] = (__bf16)uf[lm][k0 * 32 + qd * 8 + j];
        #pragma unroll
        for (int i = 0; i < 2; ++i) {
            int ot = wv * 2 + i;
            f32x4 acc = {0.f, 0.f, 0.f, 0.f};
            #pragma unroll
            for (int k0 = 0; k0 < 4; ++k0) {
                bf16x8 bf = *(const bf16x8*)(wbf + WQ_OFF + ((ot * 4 + k0) << 9) + lane * 8);
                acc = __builtin_amdgcn_mfma_f32_16x16x32_bf16(an[k0], bf, acc, 0, 0, 0);
            }
            #pragma unroll
            for (int r = 0; r < 4; ++r) {
                int s = qd * 4 + r;
                if (s < 7) slf[s][ot * 16 + lm] = acc[r];
            }
        }
        __syncthreads();
        // kq = q @ Wk -> hidl
        bf16x8 aq[4];
        #pragma unroll
        for (int k0 = 0; k0 < 4; ++k0)
            #pragma unroll
            for (int j = 0; j < 8; ++j) aq[k0][j] = (__bf16)slf[lm][k0 * 32 + qd * 8 + j];
        #pragma unroll
        for (int i = 0; i < 2; ++i) {
            int dt = wv * 2 + i;
            f32x4 acc = {0.f, 0.f, 0.f, 0.f};
            #pragma unroll
            for (int k0 = 0; k0 < 4; ++k0) {
                bf16x8 bf = *(const bf16x8*)(wbf + WKT_OFF + ((dt * 4 + k0) << 9) + lane * 8);
                acc = __builtin_amdgcn_mfma_f32_16x16x32_bf16(aq[k0], bf, acc, 0, 0, 0);
            }
            #pragma unroll
            for (int r = 0; r < 4; ++r) {
                int s = qd * 4 + r;
                if (s < 7) hidl[s][dt * 16 + lm] = acc[r];
            }
        }
        __syncthreads();
        // frag-linear bf16 store of kq*SC
        {
            int kt = t >> 6, lp = t & 63;
            int lmp = lp & 15, qdp = lp >> 4;
            uint16_t h[8];
            #pragma unroll
            for (int j = 0; j < 8; ++j)
                h[j] = (lmp < 7) ? f2bfbits(hidl[lmp][kt * 32 + qdp * 8 + j] * SC_INV) : (uint16_t)0;
            uint4 st;
            st.x = (uint32_t)h[0] | ((uint32_t)h[1] << 16);
            st.y = (uint32_t)h[2] | ((uint32_t)h[3] << 16);
            st.z = (uint32_t)h[4] | ((uint32_t)h[5] << 16);
            st.w = (uint32_t)h[6] | ((uint32_t)h[7] << 16);
            *(uint4*)(kqbf + b * 2048 + t * 8) = st;
        }
    }
}

// ---------------------------------------------------------------------------
extern "C" void kernel_launch(void* const* d_in, const int* in_sizes, int n_in,
                              void* d_out, int out_size, void* d_ws, size_t ws_size,
                              hipStream_t stream) {
    const float* x    = (const float*)d_in[0];
    const float* nz   = (const float*)d_in[1];
    const float* Wq   = (const float*)d_in[2];
    const float* Wk   = (const float*)d_in[3];
    const float* Wv   = (const float*)d_in[4];
    const float* ling = (const float*)d_in[5];
    const float* linb = (const float*)d_in[6];
    const float* lsg  = (const float*)d_in[7];
    const float* lsb  = (const float*)d_in[8];
    const float* lmg  = (const float*)d_in[9];
    const float* lmb  = (const float*)d_in[10];
    const float* Wih  = (const float*)d_in[11];
    const float* Whh  = (const float*)d_in[12];
    const float* bih  = (const float*)d_in[13];
    const float* bhh  = (const float*)d_in[14];
    const float* W1   = (const float*)d_in[15];
    const float* b1   = (const float*)d_in[16];
    const float* W2   = (const float*)d_in[17];
    const float* b2   = (const float*)d_in[18];
    const float* mu   = (const float*)d_in[19];
    const float* lsig = (const float*)d_in[20];

    char* wsb = (char*)d_ws;
    uint16_t* xn    = (uint16_t*)(wsb);                        // 67108864 B
    uint16_t* wbf   = (uint16_t*)(wsb + (size_t)67108864);     // 425984 B
    uint16_t* kqbf  = (uint16_t*)(wsb + (size_t)67534848);     // 262144 B
    float*    slots = (float*)  (wsb + (size_t)67796992);      // 229376 B
    float*    upart = (float*)  (wsb + (size_t)68026368);      // 3670016 B
    float*    cpart = (float*)  (wsb + (size_t)71696384);      // 28672 B

    k_init<<<448, 256, 0, stream>>>(nz, Wk, mu, lsig, Wq, lsg, lsb,
                                    Wih, Whh, W1, W2, Wv, slots, kqbf, wbf);
    k_prep_xn<<<4096, 256, 0, stream>>>(x, ling, linb, xn);
    for (int it = 0; it < 3; ++it) {
        float* dst = (it == 2) ? (float*)d_out : slots;
        k_attn<<<1024, 256, 0, stream>>>(xn, kqbf, upart, cpart);
        k_fused<<<64, 256, 0, stream>>>(upart, cpart, slots, wbf, bih, bhh,
                                        lmg, lmb, b1, b2, lsg, lsb,
                                        kqbf, dst, (it < 2) ? 1 : 0);
    }
}